// Round 1
// baseline (2155.735 us; speedup 1.0000x reference)
//
#include <hip/hip_runtime.h>

// RoutingCapsules on MI355X (gfx950)
// x: [B=32, Nin=2048, Din=16] f32
// W: [1, Nin=2048, Nout=64, Dout=32, Din=16] f32
// out v: [B=32, Nout=64, Dout=32] f32
//
// Strategy: 3 fused passes, each recomputing u_hat on the fly from W (one full
// 256MB W sweep per pass). Pass1: c uniform -> s1 = sum_n u_hat/64.
// Pass2: logits = u_hat . v1. Pass3: logits = u_hat . (v1+v2) (b3 = a1+a2).
// Cross-block reduction over n via fp32 atomicAdd into 256KB s buffer.

#define B_   32
#define NIN  2048
#define DIN  16
#define NOUT 64
#define DOUT 32
#define NCH  8   // n-values per block; grid = 2048/8 = 256 blocks = 1/CU

template<int PASS>
__global__ __launch_bounds__(512, 2)
void caps_pass(const float* __restrict__ W, const float* __restrict__ x,
               const float* __restrict__ v_in, float* __restrict__ s_out)
{
    const int t    = threadIdx.x;     // 0..511
    const int o    = t >> 3;          // 0..63  (capsule-out index; fixed per thread)
    const int dg   = t & 7;           // d-group
    const int d0   = dg << 2;         // 0,4,..,28
    const int lane = t & 63;
    const int nbase = blockIdx.x * NCH;

    __shared__ float xs[B_][DIN];     // x for current n, all 32 b (broadcast reads)
    __shared__ float lg[2][NOUT];     // logit exchange, double-buffered (1 barrier/b)

    float acc[B_][4];                 // 128 VGPRs, static-indexed via full unroll
#pragma unroll
    for (int b = 0; b < B_; ++b)
#pragma unroll
        for (int j = 0; j < 4; ++j) acc[b][j] = 0.f;

    for (int nn = 0; nn < NCH; ++nn) {
        const int n = nbase + nn;
        __syncthreads();  // protect xs from previous iteration's readers
        xs[t >> 4][t & 15] = x[((size_t)(t >> 4) * NIN + n) * DIN + (t & 15)];
        __syncthreads();

        // W fragment for this thread: W[n, o, d0..d0+3, 0..15] = 64 consecutive floats
        const float4* wp = (const float4*)(W + (((size_t)n * NOUT + o) * DOUT + d0) * DIN);
        float4 w[16];
#pragma unroll
        for (int k = 0; k < 16; ++k) w[k] = wp[k];

#pragma unroll
        for (int b = 0; b < B_; ++b) {
            const float4 x0 = *(const float4*)&xs[b][0];
            const float4 x1 = *(const float4*)&xs[b][4];
            const float4 x2 = *(const float4*)&xs[b][8];
            const float4 x3 = *(const float4*)&xs[b][12];
            float u[4];
#pragma unroll
            for (int j = 0; j < 4; ++j) {
                const float4 wa = w[4*j+0], wb = w[4*j+1], wc = w[4*j+2], wd = w[4*j+3];
                u[j] = wa.x*x0.x + wa.y*x0.y + wa.z*x0.z + wa.w*x0.w
                     + wb.x*x1.x + wb.y*x1.y + wb.z*x1.z + wb.w*x1.w
                     + wc.x*x2.x + wc.y*x2.y + wc.z*x2.z + wc.w*x2.w
                     + wd.x*x3.x + wd.y*x3.y + wd.z*x3.z + wd.w*x3.w;
            }
            float cw;
            if (PASS == 1) {
                cw = 1.0f / 64.0f;    // softmax(0) over 64
            } else {
                // logit[b,n,o] = sum_d u_hat * v  (v L2-resident, 256KB)
                const float4 vv = *(const float4*)&v_in[((size_t)b * NOUT + o) * DOUT + d0];
                float p = u[0]*vv.x + u[1]*vv.y + u[2]*vv.z + u[3]*vv.w;
                p += __shfl_xor(p, 1);
                p += __shfl_xor(p, 2);
                p += __shfl_xor(p, 4);     // 8-lane group: full dot over d
                if (dg == 0) lg[b & 1][o] = p;
                __syncthreads();
                // softmax over o=64 without max-sub (|logit| << 88, no overflow)
                float e = __expf(lg[b & 1][lane]);  // lane l holds column o=l
                float sm = e;
#pragma unroll
                for (int m = 1; m < 64; m <<= 1) sm += __shfl_xor(sm, m);
                cw = __shfl(e, o) / sm;    // c[b,n,o] for this thread's o
            }
#pragma unroll
            for (int j = 0; j < 4; ++j) acc[b][j] += cw * u[j];
        }
    }

    // accumulate into s[b, o, d] across n-blocks
#pragma unroll
    for (int b = 0; b < B_; ++b)
#pragma unroll
        for (int j = 0; j < 4; ++j)
            atomicAdd(&s_out[((size_t)b * NOUT + o) * DOUT + d0 + j], acc[b][j]);
}

// v = squash(s) per (b,o) row of 32 d; accumulate==1 -> vout += squash(s)
__global__ void squash_k(const float* __restrict__ s, float* __restrict__ vout,
                         int accumulate)
{
    const int idx = blockIdx.x * 256 + threadIdx.x;   // 65536 elements total
    const float val = s[idx];
    float sq = val * val;
#pragma unroll
    for (int m = 1; m < 32; m <<= 1) sq += __shfl_xor(sq, m);  // row = 32 lanes
    const float f = sq / ((1.0f + sq) * sqrtf(sq + 1e-8f));
    const float v = val * f;
    if (accumulate) vout[idx] += v;
    else            vout[idx] = v;
}

extern "C" void kernel_launch(void* const* d_in, const int* in_sizes, int n_in,
                              void* d_out, int out_size, void* d_ws, size_t ws_size,
                              hipStream_t stream)
{
    (void)in_sizes; (void)n_in; (void)out_size; (void)ws_size;
    const float* x = (const float*)d_in[0];
    const float* W = (const float*)d_in[1];
    float* out = (float*)d_out;

    float* s  = (float*)d_ws;         // 65536 f32 = 256KB
    float* vA = s + 65536;            // 65536 f32 = 256KB (v1, then v1+v2)
    const size_t sbytes = (size_t)65536 * sizeof(float);

    // ---- iter 1: uniform c -> s1 -> v1
    hipMemsetAsync(s, 0, sbytes, stream);
    caps_pass<1><<<dim3(NIN / NCH), dim3(512), 0, stream>>>(W, x, nullptr, s);
    squash_k<<<dim3(256), dim3(256), 0, stream>>>(s, vA, 0);      // vA = v1

    // ---- iter 2: logits = u.v1 -> s2 -> v2 ; vA = v1+v2
    hipMemsetAsync(s, 0, sbytes, stream);
    caps_pass<2><<<dim3(NIN / NCH), dim3(512), 0, stream>>>(W, x, vA, s);
    squash_k<<<dim3(256), dim3(256), 0, stream>>>(s, vA, 1);      // vA = v1 + v2

    // ---- iter 3: logits = u.(v1+v2) -> s3 -> out = v3
    hipMemsetAsync(s, 0, sbytes, stream);
    caps_pass<2><<<dim3(NIN / NCH), dim3(512), 0, stream>>>(W, x, vA, s);
    squash_k<<<dim3(256), dim3(256), 0, stream>>>(s, out, 0);
}